// Round 1
// 1155.655 us; speedup vs baseline: 1.1193x; 1.1193x over previous
//
#include <hip/hip_runtime.h>

#define B_ 2
#define H_ 16
#define S_ 2048
#define D_ 128

typedef __attribute__((ext_vector_type(8))) short short8;
typedef __attribute__((ext_vector_type(4))) float floatx4;

__device__ __forceinline__ unsigned short f2bf(float f) {
    union { float f; unsigned int u; } c; c.f = f;
    unsigned int u = c.u;
    u += 0x7fff + ((u >> 16) & 1);   // round-to-nearest-even
    return (unsigned short)(u >> 16);
}

// async global->LDS, 16 B/lane. LDS dest = wave-uniform base + lane*16 (m104).
// generic->AS casts via integer round-trip (CK idiom: low 32 bits of a generic
// shared-memory pointer are the LDS byte offset on amdgcn).
__device__ __forceinline__ void gld16(const void* g, void* l) {
    __builtin_amdgcn_global_load_lds(
        (const __attribute__((address_space(1))) unsigned int*)(unsigned long long)g,
        (__attribute__((address_space(3))) unsigned int*)(unsigned int)(unsigned long long)l,
        16, 0, 0);
}

// ---------------------------------------------------------------------------
// Prep 0: K fp32 [bh][s][d] -> bf16 same layout (workspace).
// ---------------------------------------------------------------------------
__global__ __launch_bounds__(256) void kbf_kernel(const float* __restrict__ k,
                                                  unsigned short* __restrict__ kw) {
    int base = blockIdx.x * 1024 + threadIdx.x;
    #pragma unroll
    for (int i = 0; i < 4; ++i) {
        int idx = base + i * 256;
        const float4* s = (const float4*)k + (size_t)idx * 2;
        float4 a = s[0], c = s[1];
        short8 y;
        y[0] = f2bf(a.x); y[1] = f2bf(a.y); y[2] = f2bf(a.z); y[3] = f2bf(a.w);
        y[4] = f2bf(c.x); y[5] = f2bf(c.y); y[6] = f2bf(c.z); y[7] = f2bf(c.w);
        ((short8*)kw)[idx] = y;
    }
}

// ---------------------------------------------------------------------------
// Prep 1: V fp32 [bh][s][d] -> V^T bf16 [bh][d][s] (workspace).
// ---------------------------------------------------------------------------
__global__ __launch_bounds__(256) void vt_kernel(const float* __restrict__ v,
                                                 unsigned short* __restrict__ vt) {
    __shared__ unsigned short tl[128][66];
    int bid = blockIdx.x;
    int bh = bid >> 5;
    int s0 = (bid & 31) << 6;
    int t = threadIdx.x;
    const float4* vp = (const float4*)(v + ((size_t)bh * S_ + s0) * D_);
    #pragma unroll
    for (int i = 0; i < 8; ++i) {
        int idx = t + i * 256;
        int r = idx >> 5;
        int d = (idx & 31) << 2;
        float4 x = vp[idx];
        tl[d + 0][r] = f2bf(x.x);
        tl[d + 1][r] = f2bf(x.y);
        tl[d + 2][r] = f2bf(x.z);
        tl[d + 3][r] = f2bf(x.w);
    }
    __syncthreads();
    unsigned short* op = vt + (size_t)bh * D_ * S_ + s0;
    #pragma unroll
    for (int i = 0; i < 16; ++i) {
        int idx = t + i * 256;
        int d = idx >> 5;
        int s2 = (idx & 31) << 1;
        unsigned int val = (unsigned int)tl[d][s2] | ((unsigned int)tl[d][s2 + 1] << 16);
        *(unsigned int*)(op + (size_t)d * S_ + s2) = val;
    }
}

// ---------------------------------------------------------------------------
// Fused attention: phase 1 computes per-row sum(exp) in registers (recompute
// pass, nothing written); phase 2 recomputes QK^T, writes normalized attn
// ONCE, and accumulates out = P@V.  Saves the 1 GB unnormalized-e HBM round
// trip of the previous 2-kernel design; costs one extra QK MFMA pass (the
// matrix pipe was 3.5% utilized).
//   LDS 40 KB: kbuf0 16K (K tile, 64x128 bf16, XOR-swizzled)
//              kbuf1 16K (phase1: K double-buffer; phase2: V^T tile 128x64)
//              pbuf   8K (wave-private P 16x64 bf16, swizzled)
// Swizzle: byte ^= (row&7)<<4, applied on the *global source address* of
// global_load_lds (LDS written linearly, m173) and on every ds_read/ds_write.
// ---------------------------------------------------------------------------

#define LOAD_BM(BB, MM, K0) do {                                              \
    _Pragma("unroll") for (int rr = 0; rr < 4; ++rr) {                        \
        _Pragma("unroll") for (int nt = 0; nt < 4; ++nt) {                    \
            BB[rr * 4 + nt] = bias_r[rr][(K0) + nt * 16];                     \
            MM[rr * 4 + nt] = mask_r[rr][(K0) + nt * 16]; } } } while (0)

#define QK_MFMA(KB, ACC) do {                                                 \
    _Pragma("unroll") for (int nt = 0; nt < 4; ++nt)                          \
        ACC[nt] = (floatx4){0.f, 0.f, 0.f, 0.f};                              \
    _Pragma("unroll") for (int kk = 0; kk < 4; ++kk) {                        \
        _Pragma("unroll") for (int nt = 0; nt < 4; ++nt) {                    \
            int r_ = nt * 16 + l16;                                           \
            short8 bfr_ = *(const short8*)((const char*)(KB) + r_ * 256 +     \
                           ((kk * 64 + g * 16) ^ ((r_ & 7) << 4)));           \
            ACC[nt] = __builtin_amdgcn_mfma_f32_16x16x32_bf16(                \
                          afr[kk], bfr_, ACC[nt], 0, 0, 0); } } } while (0)

#define ERS(BB, MM) do {                                                      \
    _Pragma("unroll") for (int rr = 0; rr < 4; ++rr) {                        \
        _Pragma("unroll") for (int nt = 0; nt < 4; ++nt) {                    \
            float e_ = MM[rr * 4 + nt]                                        \
                ? __expf(fmaf(acc[nt][rr], scale, BB[rr * 4 + nt])) : 0.f;    \
            rs[rr] += e_; } } } while (0)

__global__ __launch_bounds__(256, 3) void attn_kernel(
    const float* __restrict__ q,
    const int* __restrict__ mask,
    const float* __restrict__ bias,
    const unsigned short* __restrict__ ktw,
    const unsigned short* __restrict__ vtw,
    float* __restrict__ attn,
    float* __restrict__ out)
{
    __shared__ __align__(16) char smem[40960];
    unsigned short* kbuf0 = (unsigned short*)smem;
    unsigned short* kbuf1 = (unsigned short*)(smem + 16384);
    unsigned short* pbuf  = (unsigned short*)(smem + 32768);

    int bid = blockIdx.x;
    int qt = bid >> 5;
    int hb = bid & 31;          // bid%8 == hb&7 -> all 32 q-tiles of an (h,b)
    int h = hb >> 1;            // land on one XCD: bias/K/V L2 locality free.
    int b = hb & 1;
    int bh = b * H_ + h;
    int q0 = qt << 6;
    int t = threadIdx.x;
    int w = t >> 6;
    int lane = t & 63;
    int g = lane >> 4;
    int l16 = lane & 15;

    const unsigned short* ktw_bh = ktw + (size_t)bh * S_ * D_;
    const unsigned short* vtw_bh = vtw + (size_t)bh * D_ * S_;

    // Q A-fragments (loop-invariant): lane(g,l16) holds Q[q0+w*16+l16][kk*32+g*8+j]
    short8 afr[4];
    {
        const float* qrow = q + ((size_t)bh * S_ + q0 + w * 16 + l16) * D_;
        #pragma unroll
        for (int kk = 0; kk < 4; ++kk) {
            float4 a = *(const float4*)&qrow[kk * 32 + g * 8];
            float4 c = *(const float4*)&qrow[kk * 32 + g * 8 + 4];
            short8 f;
            f[0] = f2bf(a.x); f[1] = f2bf(a.y); f[2] = f2bf(a.z); f[3] = f2bf(a.w);
            f[4] = f2bf(c.x); f[5] = f2bf(c.y); f[6] = f2bf(c.z); f[7] = f2bf(c.w);
            afr[kk] = f;
        }
    }

    // bias/mask per-lane row pointers in accumulator layout:
    // rows q0+w*16+g*4+rr, col = l16 (+ k0 + nt*16 at load time)
    const float* bias_r[4];
    const int*   mask_r[4];
    {
        const float* bh_bias = bias + (size_t)h * S_ * S_;
        const int*   b_mask  = mask + (size_t)b * S_ * S_;
        #pragma unroll
        for (int rr = 0; rr < 4; ++rr) {
            int row = q0 + w * 16 + g * 4 + rr;
            bias_r[rr] = bh_bias + (size_t)row * S_ + l16;
            mask_r[rr] = b_mask  + (size_t)row * S_ + l16;
        }
    }

    // staging: wave w covers its quarter of the tile; source address carries
    // the inverse swizzle so linear LDS writes land swizzled.
    auto stage_k = [&](int k0, unsigned short* kb) {
        int rsub = lane >> 4;
        int cb = (lane & 15) << 4;
        #pragma unroll
        for (int c = 0; c < 4; ++c) {
            int r = w * 16 + c * 4 + rsub;
            const char* src = (const char*)ktw_bh + (((size_t)(k0 + r)) << 8)
                              + (cb ^ ((r & 7) << 4));
            gld16(src, (char*)kb + w * 4096 + c * 1024);
        }
    };
    auto stage_v = [&](int k0) {
        int dsub = lane >> 3;
        int cb = (lane & 7) << 4;
        #pragma unroll
        for (int c = 0; c < 4; ++c) {
            int d = w * 32 + c * 8 + dsub;
            const char* src = (const char*)vtw_bh + (size_t)d * (S_ * 2)
                              + (size_t)(k0 * 2) + (cb ^ ((d & 7) << 4));
            gld16(src, (char*)kbuf1 + w * 4096 + c * 1024);
        }
    };

    const float scale = 0.08838834764831845f;  // 1/sqrt(128)
    float rs[4] = {0.f, 0.f, 0.f, 0.f};
    float bbA[16], bbB[16];
    int   mmA[16], mmB[16];

    // ---------------- phase 1: row sums only ----------------
    stage_k(0, kbuf0);
    LOAD_BM(bbA, mmA, 0);
    __syncthreads();

    #pragma unroll 1
    for (int ktp = 0; ktp < 16; ++ktp) {
        int kt0 = ktp << 1;
        // even iter: read kbuf0; stage kt0+1 -> kbuf1; prefetch b/m(kt0+1)
        stage_k((kt0 + 1) << 6, kbuf1);
        LOAD_BM(bbB, mmB, (kt0 + 1) << 6);
        {
            floatx4 acc[4];
            QK_MFMA(kbuf0, acc);
            ERS(bbA, mmA);
        }
        __syncthreads();
        // odd iter: read kbuf1; stage kt0+2 -> kbuf0; prefetch b/m(kt0+2)
        if (kt0 < 30) {
            stage_k((kt0 + 2) << 6, kbuf0);
            LOAD_BM(bbA, mmA, (kt0 + 2) << 6);
        }
        {
            floatx4 acc[4];
            QK_MFMA(kbuf1, acc);
            ERS(bbB, mmB);
        }
        __syncthreads();
    }

    // reduce row sums across the 16 lanes sharing each row; rinv in registers
    float rinv[4];
    #pragma unroll
    for (int rr = 0; rr < 4; ++rr) {
        float s = rs[rr];
        s += __shfl_xor(s, 1, 16);
        s += __shfl_xor(s, 2, 16);
        s += __shfl_xor(s, 4, 16);
        s += __shfl_xor(s, 8, 16);
        rinv[rr] = s > 0.f ? 1.0f / s : 0.f;
    }

    // ---------------- phase 2: normalized attn + PV ----------------
    floatx4 oacc[8];
    #pragma unroll
    for (int nt = 0; nt < 8; ++nt) oacc[nt] = (floatx4){0.f, 0.f, 0.f, 0.f};

    stage_k(0, kbuf0);
    stage_v(0);
    LOAD_BM(bbA, mmA, 0);
    __syncthreads();

    float* attn_r = attn + (size_t)bh * S_ * S_
                  + (size_t)(q0 + w * 16 + g * 4) * S_ + l16;

    #pragma unroll 1
    for (int kt = 0; kt < 32; ++kt) {
        int k0 = kt << 6;
        floatx4 acc[4];
        QK_MFMA(kbuf0, acc);

        // e -> p; stash p as bf16 in the wave-private pbuf (swizzled)
        float p[16];
        #pragma unroll
        for (int rr = 0; rr < 4; ++rr) {
            #pragma unroll
            for (int nt = 0; nt < 4; ++nt) {
                float e_ = mmA[rr * 4 + nt]
                    ? __expf(fmaf(acc[nt][rr], scale, bbA[rr * 4 + nt])) : 0.f;
                float pv_ = e_ * rinv[rr];
                p[rr * 4 + nt] = pv_;
                int prow = g * 4 + rr;
                *(unsigned short*)((char*)pbuf + (w << 11) + prow * 128 +
                    ((nt * 32 + (l16 << 1)) ^ ((prow & 7) << 4))) = f2bf(pv_);
            }
        }
        if (kt < 31) LOAD_BM(bbA, mmA, k0 + 64);   // covered by PV MFMA below

        // PV: A = P rows (wave-private LDS), B = V^T rows from kbuf1
        #pragma unroll
        for (int kk = 0; kk < 2; ++kk) {
            short8 pa = *(const short8*)((const char*)pbuf + (w << 11) +
                          l16 * 128 + ((kk * 64 + g * 16) ^ ((l16 & 7) << 4)));
            #pragma unroll
            for (int nt = 0; nt < 8; ++nt) {
                int d_ = nt * 16 + l16;
                short8 vf = *(const short8*)((const char*)kbuf1 + d_ * 128 +
                              ((kk * 64 + g * 16) ^ ((d_ & 7) << 4)));
                oacc[nt] = __builtin_amdgcn_mfma_f32_16x16x32_bf16(pa, vf, oacc[nt], 0, 0, 0);
            }
        }
        __syncthreads();                 // all waves done with kbuf0/kbuf1
        if (kt < 31) { stage_k(k0 + 64, kbuf0); stage_v(k0 + 64); }
        // attn store overlaps the async staging
        #pragma unroll
        for (int rr = 0; rr < 4; ++rr)
            #pragma unroll
            for (int nt = 0; nt < 4; ++nt)
                attn_r[rr * S_ + k0 + nt * 16] = p[rr * 4 + nt];
        __syncthreads();                 // drains stage (vmcnt) for next iter
    }

    float* op = out + ((size_t)bh * S_ + q0 + w * 16 + g * 4) * D_ + l16;
    #pragma unroll
    for (int nt = 0; nt < 8; ++nt)
        #pragma unroll
        for (int rr = 0; rr < 4; ++rr)
            op[(size_t)rr * D_ + nt * 16] = oacc[nt][rr];
}

extern "C" void kernel_launch(void* const* d_in, const int* in_sizes, int n_in,
                              void* d_out, int out_size, void* d_ws, size_t ws_size,
                              hipStream_t stream) {
    (void)in_sizes; (void)n_in; (void)out_size; (void)ws_size;
    const float* q    = (const float*)d_in[0];
    const float* k    = (const float*)d_in[1];
    const float* v    = (const float*)d_in[2];
    const int*   mask = (const int*)d_in[3];
    const float* bias = (const float*)d_in[4];

    float* out  = (float*)d_out;
    float* attn = out + (size_t)B_ * H_ * S_ * D_;

    // workspace: K-bf16 (16 MiB) + V^T-bf16 (16 MiB) = 32 MiB
    unsigned short* ktw = (unsigned short*)d_ws;
    unsigned short* vtw = ktw + (size_t)B_ * H_ * S_ * D_;

    kbf_kernel<<<1024, 256, 0, stream>>>(k, ktw);
    vt_kernel<<<1024, 256, 0, stream>>>(v, vtw);
    attn_kernel<<<1024, 256, 0, stream>>>(q, mask, bias, ktw, vtw, attn, out);
}